// Round 4
// baseline (199.129 us; speedup 1.0000x reference)
//
#include <hip/hip_runtime.h>

// B=4, C=12, D=32, H=128, W=128. S = D*H*W = 524288 voxels per b.
// R4 = R3 resubmit (infra failure) + LDS pad fix (257-float rows, conflict-free).
// Register-lean single pass: exp2 in place (no max-sub; inputs N(0,1) so
// |x|<6 is fp32-safe), horizontal per-channel accumulation (31 scalars),
// log-product trick for exc-CE (11 logs -> 1), wave-uniform switch for
// p[id1]/p[id2] extraction, LDS-transpose block reduction (no shuffle tree).

#define S4 131072           // S/4 float4 groups per (b,c) plane
#define BLOCKS_PER_B 256    // 2 float4-groups (8 voxels) per thread
#define THREADS 256
#define NVOX 524288.0f
#define SMOOTH 1e-5f
#define L2E 1.4426950408889634f
#define LN2 0.6931471805599453f

__global__ void zero_acc(float* __restrict__ acc) {
  acc[blockIdx.x * 256 + threadIdx.x] = 0.f;   // 2048 floats
}

// Per-voxel scalar tail; CM in {x,y,z,w}. All CE sums in log2 units.
#define TAIL(CM) {                                                             \
  const int tv = tg.CM;                                                        \
  const bool t0 = (tv == 0), t1 = (tv == id1), t2 = (tv == id2);               \
  c1f += t1 ? 1.f : 0.f;  c2f += t2 ? 1.f : 0.f;                               \
  p0S += t0 ? g0.CM : 0.f; p1S += t1 ? g1.CM : 0.f; p2S += t2 ? g2.CM : 0.f;   \
  const float pt = t1 ? g1.CM : (t2 ? g2.CM : 0.f);                            \
  cesE2 += __builtin_amdgcn_logf(prod.CM * __builtin_amdgcn_rcpf(1.f + pt));   \
  const float s3 = __builtin_amdgcn_exp2f(g0.CM * L2E)                         \
                 + __builtin_amdgcn_exp2f(g1.CM * L2E)                         \
                 + __builtin_amdgcn_exp2f(g2.CM * L2E);                        \
  const float gt = t0 ? g0.CM : (t1 ? g1.CM : g2.CM);                          \
  ces2 += __builtin_amdgcn_logf(s3) - gt * L2E;                               \
}

// acc slot layout (64B-spread): acc[((b*32+v))<<4]
//  v: 0..11 aZ[c]=sum p_c^2   12..23 aP[c]=sum p_c
//  24 ces2  25 cesE2  26 c1  27 c2  28 p0S  29 p1S  30 p2S  31 pad
__global__ __launch_bounds__(THREADS, 4)
void marg_main(const float4* __restrict__ inp, const int4* __restrict__ tgtp,
               const int* __restrict__ task_id, float* __restrict__ acc) {
  const int b   = blockIdx.x / BLOCKS_PER_B;
  const int blk = blockIdx.x % BLOCKS_PER_B;
  const int t   = task_id[b];
  const int id1 = (t <= 4) ? 2*t + 1 : t + 5;
  const int id2 = (t <= 3) ? 2*t + 2 : -1;
  const bool v2 = (id2 >= 0);

  const float4* inB = inp  + (size_t)b * 12 * S4;
  const int4*   tgB = tgtp + (size_t)b * S4;

  float aZ[12], aP[12];
  #pragma unroll
  for (int c = 0; c < 12; ++c) { aZ[c] = 0.f; aP[c] = 0.f; }
  float ces2=0.f, cesE2=0.f, c1f=0.f, c2f=0.f, p0S=0.f, p1S=0.f, p2S=0.f;

  #pragma unroll 1
  for (int it = 0; it < 2; ++it) {
    const int s = (blk * 2 + it) * THREADS + (int)threadIdx.x;
    float4 e[12];
    #pragma unroll
    for (int c = 0; c < 12; ++c) e[c] = inB[c * S4 + s];
    const int4 tg = tgB[s];

    // exp2 in place (softmax without max-subtraction: |x|<~6 is safe)
    #pragma unroll
    for (int c = 0; c < 12; ++c) {
      e[c].x = __builtin_amdgcn_exp2f(e[c].x * L2E);
      e[c].y = __builtin_amdgcn_exp2f(e[c].y * L2E);
      e[c].z = __builtin_amdgcn_exp2f(e[c].z * L2E);
      e[c].w = __builtin_amdgcn_exp2f(e[c].w * L2E);
    }
    float4 es = e[0];
    #pragma unroll
    for (int c = 1; c < 12; ++c) {
      es.x += e[c].x; es.y += e[c].y; es.z += e[c].z; es.w += e[c].w;
    }
    float4 r;
    r.x = __builtin_amdgcn_rcpf(es.x); r.y = __builtin_amdgcn_rcpf(es.y);
    r.z = __builtin_amdgcn_rcpf(es.z); r.w = __builtin_amdgcn_rcpf(es.w);

    float4 prod = make_float4(1.f, 1.f, 1.f, 1.f);
    #pragma unroll
    for (int c = 0; c < 12; ++c) {
      float4 p;
      p.x = e[c].x * r.x; p.y = e[c].y * r.y;
      p.z = e[c].z * r.z; p.w = e[c].w * r.w;
      aZ[c] += (p.x*p.x + p.y*p.y) + (p.z*p.z + p.w*p.w);
      aP[c] += (p.x + p.y) + (p.z + p.w);
      if (c > 0) {   // prod *= (1+p)
        prod.x = fmaf(prod.x, p.x, prod.x);
        prod.y = fmaf(prod.y, p.y, prod.y);
        prod.z = fmaf(prod.z, p.z, prod.z);
        prod.w = fmaf(prod.w, p.w, prod.w);
      }
    }

    // wave-uniform extraction of e[id1], e[id2]
    float4 ge1, ge2;
    switch (id1) {
      case 1:  ge1 = e[1];  break;  case 3:  ge1 = e[3];  break;
      case 5:  ge1 = e[5];  break;  case 7:  ge1 = e[7];  break;
      case 9:  ge1 = e[9];  break;  case 10: ge1 = e[10]; break;
      default: ge1 = e[11]; break;
    }
    switch (id2) {
      case 2:  ge2 = e[2];  break;  case 4:  ge2 = e[4];  break;
      case 6:  ge2 = e[6];  break;  case 8:  ge2 = e[8];  break;
      default: ge2 = make_float4(0.f, 0.f, 0.f, 0.f); break;
    }
    float4 g0, g1, g2;
    g0.x = e[0].x * r.x; g0.y = e[0].y * r.y; g0.z = e[0].z * r.z; g0.w = e[0].w * r.w;
    g1.x = ge1.x * r.x;  g1.y = ge1.y * r.y;  g1.z = ge1.z * r.z;  g1.w = ge1.w * r.w;
    g2.x = v2 ? ge2.x * r.x : -1e30f;  g2.y = v2 ? ge2.y * r.y : -1e30f;
    g2.z = v2 ? ge2.z * r.z : -1e30f;  g2.w = v2 ? ge2.w * r.w : -1e30f;

    TAIL(x); TAIL(y); TAIL(z); TAIL(w);
  }

  // ---- block reduction: LDS transpose, no shuffle tree ----
  float vals[32];
  #pragma unroll
  for (int c = 0; c < 12; ++c) { vals[c] = aZ[c]; vals[12 + c] = aP[c]; }
  vals[24] = ces2; vals[25] = cesE2; vals[26] = c1f; vals[27] = c2f;
  vals[28] = p0S;  vals[29] = p1S;   vals[30] = p2S; vals[31] = 0.f;

  // 257-float rows: write bank=(v+tid)%32, read bank=(val+k)%32 -> conflict-free
  __shared__ float red[32][257];
  #pragma unroll
  for (int v = 0; v < 32; ++v) red[v][threadIdx.x] = vals[v];
  __syncthreads();

  const int val = threadIdx.x & 31;
  const int seg = threadIdx.x >> 5;      // 0..7: which 32-thread segment
  const float* row = red[val];
  float ssum = 0.f;
  #pragma unroll
  for (int k = 0; k < 32; ++k) ssum += row[seg * 32 + k];
  ssum += __shfl_down(ssum, 32);         // fold the wave's two segments
  if ((threadIdx.x & 63) < 32)
    atomicAdd(acc + (((b * 32 + val)) << 4), ssum);
}

__global__ void finalize(const float* __restrict__ acc,
                         const int* __restrict__ task_id,
                         float* __restrict__ out) {
  if (threadIdx.x != 0) return;
  float lmd = 0.f, lmce = 0.f, led = 0.f, lece = 0.f;
  for (int b = 0; b < 4; ++b) {
    const int t   = task_id[b];
    const int id1 = (t <= 4) ? 2*t + 1 : t + 5;
    const int id2 = (t <= 3) ? 2*t + 2 : -1;
    #define A(v) acc[((b * 32 + (v))) << 4]

    lmce += A(24) * LN2 / NVOX;
    lece += A(25) * LN2 / NVOX;

    const float c1 = A(26), c2 = A(27);
    const float y0 = NVOX - c1 - c2;
    const float d0 = (2.f*A(28) + SMOOTH) / (A(0)   + y0 + SMOOTH);
    const float d1 = (2.f*A(29) + SMOOTH) / (A(id1) + c1 + SMOOTH);
    float d2 = 1.f;
    if (id2 >= 0)
      d2 = (2.f*A(30) + SMOOTH) / (A(id2) + c2 + SMOOTH);
    lmd += (1.f - d0) + (1.f - d1) + (1.f - d2);

    led += SMOOTH / (A(0) + SMOOTH);
    for (int c = 1; c < 12; ++c) {
      const float ptc  = (c == id1) ? A(29) : ((c == id2) ? A(30) : 0.f);
      const float cntc = (c == id1) ? c1    : ((c == id2) ? c2    : 0.f);
      const float inter = A(12 + c) - ptc;
      const float ye    = NVOX - cntc;
      led += (2.f*inter + SMOOTH) / (A(c) + ye + SMOOTH);
    }
    #undef A
  }
  out[0] = lmd  * 0.25f;
  out[1] = lmce * 0.25f;
  out[2] = led  * 0.25f;
  out[3] = lece * 0.25f;
}

extern "C" void kernel_launch(void* const* d_in, const int* in_sizes, int n_in,
                              void* d_out, int out_size, void* d_ws, size_t ws_size,
                              hipStream_t stream) {
  const float* inputs  = (const float*)d_in[0];
  const int*   targets = (const int*)d_in[1];
  const int*   task_id = (const int*)d_in[2];
  float* out = (float*)d_out;
  float* acc = (float*)d_ws;

  zero_acc<<<dim3(8), 256, 0, stream>>>(acc);
  marg_main<<<dim3(4 * BLOCKS_PER_B), THREADS, 0, stream>>>(
      (const float4*)inputs, (const int4*)targets, task_id, acc);
  finalize<<<1, 64, 0, stream>>>(acc, task_id, out);
}

// Round 7
// 181.757 us; speedup vs baseline: 1.0956x; 1.0956x over previous
//
#include <hip/hip_runtime.h>

// B=4, C=12, D=32, H=128, W=128. S = D*H*W = 524288 voxels per b.
// R7: same theory as R5/R6 (R4 was latency-bound: VGPR=60 showed the compiler
// serialized the 12 plane loads; only ~7us of VALU issue in a 75us kernel) but
// branch-free: no switch extraction (re-load planes id1/id2 directly -> L1
// hits), NITER=2 fully unrolled with ALL 30 wave-loads issued before any
// consumer (explicit MLP), launch_bounds(256,2) so the allocator has no
// pressure to re-serialize, tiny shuffle-tree epilogue (512B LDS).

#define S4 131072           // S/4 float4 groups per (b,c) plane
#define BLOCKS_PER_B 256
#define THREADS 256
#define NVOX 524288.0f
#define SMOOTH 1e-5f
#define L2E 1.4426950408889634f
#define LN2 0.6931471805599453f

#define WRED(v) { v += __shfl_down(v,32); v += __shfl_down(v,16); \
                  v += __shfl_down(v,8);  v += __shfl_down(v,4);  \
                  v += __shfl_down(v,2);  v += __shfl_down(v,1); }

__global__ void zero_acc(float* __restrict__ acc) {
  acc[blockIdx.x * 256 + threadIdx.x] = 0.f;   // 2048 floats
}

// Per-voxel scalar tail; CM in {x,y,z,w}. CE sums in log2 units.
// When id2==-1: t2 is always false, g2=-1e30 -> exp2 term vanishes.
#define TAIL(CM) {                                                             \
  const int tv = tg.CM;                                                        \
  const bool t0 = (tv == 0), t1 = (tv == id1), t2 = (tv == id2);               \
  c1f += t1 ? 1.f : 0.f;  c2f += t2 ? 1.f : 0.f;                               \
  p0S += t0 ? g0.CM : 0.f; p1S += t1 ? g1.CM : 0.f; p2S += t2 ? g2.CM : 0.f;   \
  const float pt = t1 ? g1.CM : (t2 ? g2.CM : 0.f);                            \
  cesE2 += __builtin_amdgcn_logf(prod.CM * __builtin_amdgcn_rcpf(1.f + pt));   \
  const float s3 = __builtin_amdgcn_exp2f(g0.CM * L2E)                         \
                 + __builtin_amdgcn_exp2f(g1.CM * L2E)                         \
                 + __builtin_amdgcn_exp2f(g2.CM * L2E);                        \
  const float gt = t0 ? g0.CM : (t1 ? g1.CM : g2.CM);                          \
  ces2 += __builtin_amdgcn_logf(s3) - gt * L2E;                                \
}

// Straight-line per-group compute. E[12] raw logits (consumed), GE1/GE2 raw
// logits of planes id1/id2c, TG int4 targets.
#define COMPUTE(E, GE1, GE2, TG) {                                             \
  _Pragma("unroll")                                                            \
  for (int c = 0; c < 12; ++c) {                                               \
    E[c].x = __builtin_amdgcn_exp2f(E[c].x * L2E);                             \
    E[c].y = __builtin_amdgcn_exp2f(E[c].y * L2E);                             \
    E[c].z = __builtin_amdgcn_exp2f(E[c].z * L2E);                             \
    E[c].w = __builtin_amdgcn_exp2f(E[c].w * L2E);                             \
  }                                                                            \
  float4 es = E[0];                                                            \
  _Pragma("unroll")                                                            \
  for (int c = 1; c < 12; ++c) {                                               \
    es.x += E[c].x; es.y += E[c].y; es.z += E[c].z; es.w += E[c].w;            \
  }                                                                            \
  float4 r;                                                                    \
  r.x = __builtin_amdgcn_rcpf(es.x); r.y = __builtin_amdgcn_rcpf(es.y);        \
  r.z = __builtin_amdgcn_rcpf(es.z); r.w = __builtin_amdgcn_rcpf(es.w);        \
  float4 prod = make_float4(1.f, 1.f, 1.f, 1.f);                               \
  _Pragma("unroll")                                                            \
  for (int c = 0; c < 12; ++c) {                                               \
    float4 p;                                                                  \
    p.x = E[c].x * r.x; p.y = E[c].y * r.y;                                    \
    p.z = E[c].z * r.z; p.w = E[c].w * r.w;                                    \
    aZ[c] += (p.x*p.x + p.y*p.y) + (p.z*p.z + p.w*p.w);                        \
    aP[c] += (p.x + p.y) + (p.z + p.w);                                        \
    if (c > 0) {                                                               \
      prod.x = fmaf(prod.x, p.x, prod.x);                                      \
      prod.y = fmaf(prod.y, p.y, prod.y);                                      \
      prod.z = fmaf(prod.z, p.z, prod.z);                                      \
      prod.w = fmaf(prod.w, p.w, prod.w);                                      \
    }                                                                          \
  }                                                                            \
  float4 g0, g1, g2;                                                           \
  g0.x = E[0].x * r.x; g0.y = E[0].y * r.y;                                    \
  g0.z = E[0].z * r.z; g0.w = E[0].w * r.w;                                    \
  g1.x = __builtin_amdgcn_exp2f(GE1.x * L2E) * r.x;                            \
  g1.y = __builtin_amdgcn_exp2f(GE1.y * L2E) * r.y;                            \
  g1.z = __builtin_amdgcn_exp2f(GE1.z * L2E) * r.z;                            \
  g1.w = __builtin_amdgcn_exp2f(GE1.w * L2E) * r.w;                            \
  g2.x = v2 ? __builtin_amdgcn_exp2f(GE2.x * L2E) * r.x : -1e30f;              \
  g2.y = v2 ? __builtin_amdgcn_exp2f(GE2.y * L2E) * r.y : -1e30f;              \
  g2.z = v2 ? __builtin_amdgcn_exp2f(GE2.z * L2E) * r.z : -1e30f;              \
  g2.w = v2 ? __builtin_amdgcn_exp2f(GE2.w * L2E) * r.w : -1e30f;              \
  const int4 tg = TG;                                                          \
  TAIL(x); TAIL(y); TAIL(z); TAIL(w);                                          \
}

// acc slot layout (64B-spread): acc[(b*32+v)<<4]
//  v: 0..11 aZ[c]=sum p_c^2   12..23 aP[c]=sum p_c
//  24 ces2  25 cesE2  26 c1  27 c2  28 p0S  29 p1S  30 p2S  31 pad
__global__ __launch_bounds__(THREADS, 2)
void marg_main(const float4* __restrict__ inp, const int4* __restrict__ tgtp,
               const int* __restrict__ task_id, float* __restrict__ acc) {
  const int b   = blockIdx.x / BLOCKS_PER_B;
  const int blk = blockIdx.x % BLOCKS_PER_B;
  const int t   = task_id[b];
  const int id1 = (t <= 4) ? 2*t + 1 : t + 5;
  const int id2 = (t <= 3) ? 2*t + 2 : -1;
  const bool v2 = (id2 >= 0);
  const int id2c = v2 ? id2 : 0;   // safe plane for the dead load

  const float4* inB = inp  + (size_t)b * 12 * S4;
  const int4*   tgB = tgtp + (size_t)b * S4;

  float aZ[12], aP[12];
  #pragma unroll
  for (int c = 0; c < 12; ++c) { aZ[c] = 0.f; aP[c] = 0.f; }
  float ces2=0.f, cesE2=0.f, c1f=0.f, c2f=0.f, p0S=0.f, p1S=0.f, p2S=0.f;

  const int s0 = blk * (2 * THREADS) + (int)threadIdx.x;
  const int s1 = s0 + THREADS;

  // ---- issue ALL loads before any consumer (30 wave-loads in flight) ----
  float4 xa[12], xb[12];
  #pragma unroll
  for (int c = 0; c < 12; ++c) xa[c] = inB[(size_t)c * S4 + s0];
  float4 ga1 = inB[(size_t)id1 * S4 + s0];
  float4 ga2 = inB[(size_t)id2c * S4 + s0];
  const int4 ta = tgB[s0];
  #pragma unroll
  for (int c = 0; c < 12; ++c) xb[c] = inB[(size_t)c * S4 + s1];
  float4 gb1 = inB[(size_t)id1 * S4 + s1];
  float4 gb2 = inB[(size_t)id2c * S4 + s1];
  const int4 tb = tgB[s1];

  COMPUTE(xa, ga1, ga2, ta);
  COMPUTE(xb, gb1, gb2, tb);

  // ---- block reduction: shuffle tree + tiny LDS ----
  WRED(ces2); WRED(cesE2); WRED(c1f); WRED(c2f);
  WRED(p0S);  WRED(p1S);   WRED(p2S);
  #pragma unroll
  for (int c = 0; c < 12; ++c) { WRED(aZ[c]); WRED(aP[c]); }

  __shared__ float red[4][32];
  const int lane = threadIdx.x & 63;
  const int wv   = threadIdx.x >> 6;
  if (lane == 0) {
    float* rw = red[wv];
    #pragma unroll
    for (int c = 0; c < 12; ++c) { rw[c] = aZ[c]; rw[12 + c] = aP[c]; }
    rw[24] = ces2; rw[25] = cesE2; rw[26] = c1f; rw[27] = c2f;
    rw[28] = p0S;  rw[29] = p1S;   rw[30] = p2S; rw[31] = 0.f;
  }
  __syncthreads();
  if (threadIdx.x < 32) {
    const float sv = red[0][threadIdx.x] + red[1][threadIdx.x]
                   + red[2][threadIdx.x] + red[3][threadIdx.x];
    atomicAdd(acc + ((b * 32 + (int)threadIdx.x) << 4), sv);
  }
}

__global__ void finalize(const float* __restrict__ acc,
                         const int* __restrict__ task_id,
                         float* __restrict__ out) {
  if (threadIdx.x != 0) return;
  float lmd = 0.f, lmce = 0.f, led = 0.f, lece = 0.f;
  for (int b = 0; b < 4; ++b) {
    const int t   = task_id[b];
    const int id1 = (t <= 4) ? 2*t + 1 : t + 5;
    const int id2 = (t <= 3) ? 2*t + 2 : -1;
    #define A(v) acc[((b * 32 + (v))) << 4]

    lmce += A(24) * LN2 / NVOX;
    lece += A(25) * LN2 / NVOX;

    const float c1 = A(26), c2 = A(27);
    const float y0 = NVOX - c1 - c2;
    const float d0 = (2.f*A(28) + SMOOTH) / (A(0)   + y0 + SMOOTH);
    const float d1 = (2.f*A(29) + SMOOTH) / (A(id1) + c1 + SMOOTH);
    float d2 = 1.f;
    if (id2 >= 0)
      d2 = (2.f*A(30) + SMOOTH) / (A(id2) + c2 + SMOOTH);
    lmd += (1.f - d0) + (1.f - d1) + (1.f - d2);

    led += SMOOTH / (A(0) + SMOOTH);
    for (int c = 1; c < 12; ++c) {
      const float ptc  = (c == id1) ? A(29) : ((c == id2) ? A(30) : 0.f);
      const float cntc = (c == id1) ? c1    : ((c == id2) ? c2    : 0.f);
      const float inter = A(12 + c) - ptc;
      const float ye    = NVOX - cntc;
      led += (2.f*inter + SMOOTH) / (A(c) + ye + SMOOTH);
    }
    #undef A
  }
  out[0] = lmd  * 0.25f;
  out[1] = lmce * 0.25f;
  out[2] = led  * 0.25f;
  out[3] = lece * 0.25f;
}

extern "C" void kernel_launch(void* const* d_in, const int* in_sizes, int n_in,
                              void* d_out, int out_size, void* d_ws, size_t ws_size,
                              hipStream_t stream) {
  const float* inputs  = (const float*)d_in[0];
  const int*   targets = (const int*)d_in[1];
  const int*   task_id = (const int*)d_in[2];
  float* out = (float*)d_out;
  float* acc = (float*)d_ws;

  zero_acc<<<dim3(8), 256, 0, stream>>>(acc);
  marg_main<<<dim3(4 * BLOCKS_PER_B), THREADS, 0, stream>>>(
      (const float4*)inputs, (const int4*)targets, task_id, acc);
  finalize<<<1, 64, 0, stream>>>(acc, task_id, out);
}

// Round 8
// 172.452 us; speedup vs baseline: 1.1547x; 1.0540x over previous
//
#include <hip/hip_runtime.h>

// B=4, C=12, D=32, H=128, W=128. S = D*H*W = 524288 voxels per b.
// R8: LDS-staged streaming. R1/R4/R7 all plateaued at ~58us / ~930 GB/s:
// the pre-RA scheduler serializes register-destined global loads (R4's
// VGPR=60 is the smoking gun) no matter how the source batches them.
// global_load_lds has NO register destination -> 12 dependency-free 16B
// direct-to-LDS loads per thread (48KB/block in flight vs ~9KB/CU needed
// for full HBM BW). __syncthreads' vmcnt(0) drain is the tile join; 3
// resident blocks/CU (48.5KB LDS) overlap stage/compute across blocks.

#define S4 131072           // S/4 float4 groups per (b,c) plane
#define BLOCKS_PER_B 256
#define THREADS 256
#define TILES_PER_BLOCK 2
#define NVOX 524288.0f
#define SMOOTH 1e-5f
#define L2E 1.4426950408889634f
#define LN2 0.6931471805599453f

#define WRED(v) { v += __shfl_down(v,32); v += __shfl_down(v,16); \
                  v += __shfl_down(v,8);  v += __shfl_down(v,4);  \
                  v += __shfl_down(v,2);  v += __shfl_down(v,1); }

__global__ void zero_acc(float* __restrict__ acc) {
  acc[blockIdx.x * 256 + threadIdx.x] = 0.f;   // 2048 floats
}

// 16B global->LDS direct copy. lds base must be wave-uniform; HW writes
// ldsbase + lane*16 (m97/m104 semantics).
__device__ __forceinline__ void gload_lds16(const float4* g, float4* ldsbase) {
  __builtin_amdgcn_global_load_lds(
      (const __attribute__((address_space(1))) void*)g,
      (__attribute__((address_space(3))) void*)ldsbase, 16, 0, 0);
}

// Per-voxel scalar tail; CM in {x,y,z,w}. CE sums in log2 units.
#define TAIL(CM) {                                                             \
  const int tv = tg.CM;                                                        \
  const bool t0 = (tv == 0), t1 = (tv == id1), t2 = (tv == id2);               \
  c1f += t1 ? 1.f : 0.f;  c2f += t2 ? 1.f : 0.f;                               \
  p0S += t0 ? g0.CM : 0.f; p1S += t1 ? g1.CM : 0.f; p2S += t2 ? g2.CM : 0.f;   \
  const float pt = t1 ? g1.CM : (t2 ? g2.CM : 0.f);                            \
  cesE2 += __builtin_amdgcn_logf(prod.CM * __builtin_amdgcn_rcpf(1.f + pt));   \
  const float s3 = __builtin_amdgcn_exp2f(g0.CM * L2E)                         \
                 + __builtin_amdgcn_exp2f(g1.CM * L2E)                         \
                 + __builtin_amdgcn_exp2f(g2.CM * L2E);                        \
  const float gt = t0 ? g0.CM : (t1 ? g1.CM : g2.CM);                          \
  ces2 += __builtin_amdgcn_logf(s3) - gt * L2E;                                \
}

// acc slot layout (64B-spread): acc[(b*32+v)<<4]
//  v: 0..11 aZ[c]=sum p_c^2   12..23 aP[c]=sum p_c
//  24 ces2  25 cesE2  26 c1  27 c2  28 p0S  29 p1S  30 p2S  31 pad
__global__ __launch_bounds__(THREADS, 3)
void marg_main(const float4* __restrict__ inp, const int4* __restrict__ tgtp,
               const int* __restrict__ task_id, float* __restrict__ acc) {
  __shared__ float4 ldsA[12][THREADS];   // 48 KB tile: [channel][voxel-group]
  __shared__ float red[4][32];

  const int b    = blockIdx.x / BLOCKS_PER_B;
  const int blk  = blockIdx.x % BLOCKS_PER_B;
  const int tid  = threadIdx.x;
  const int wv   = tid >> 6;
  const int lane = tid & 63;
  const int t    = task_id[b];
  const int id1  = (t <= 4) ? 2*t + 1 : t + 5;
  const int id2  = (t <= 3) ? 2*t + 2 : -1;
  const bool v2  = (id2 >= 0);
  const int id2c = v2 ? id2 : 0;   // safe LDS row when id2 invalid

  const float4* inB = inp  + (size_t)b * 12 * S4;
  const int4*   tgB = tgtp + (size_t)b * S4;

  float aZ[12], aP[12];
  #pragma unroll
  for (int c = 0; c < 12; ++c) { aZ[c] = 0.f; aP[c] = 0.f; }
  float ces2=0.f, cesE2=0.f, c1f=0.f, c2f=0.f, p0S=0.f, p1S=0.f, p2S=0.f;

  #pragma unroll 1
  for (int it = 0; it < TILES_PER_BLOCK; ++it) {
    const int g0i = (blk * TILES_PER_BLOCK + it) * THREADS;

    // ---- stage: 12 dependency-free direct-to-LDS loads per thread ----
    #pragma unroll
    for (int c = 0; c < 12; ++c)
      gload_lds16(&inB[(size_t)c * S4 + g0i + tid], &ldsA[c][wv << 6]);
    const int4 tg = tgB[g0i + tid];       // drained by the barrier below too
    __syncthreads();                      // vmcnt(0): tile resident in LDS

    // ---- compute from LDS ----
    float4 xv[12];
    #pragma unroll
    for (int c = 0; c < 12; ++c) {
      const float4 v = ldsA[c][tid];
      xv[c].x = __builtin_amdgcn_exp2f(v.x * L2E);
      xv[c].y = __builtin_amdgcn_exp2f(v.y * L2E);
      xv[c].z = __builtin_amdgcn_exp2f(v.z * L2E);
      xv[c].w = __builtin_amdgcn_exp2f(v.w * L2E);
    }
    float4 es = xv[0];
    #pragma unroll
    for (int c = 1; c < 12; ++c) {
      es.x += xv[c].x; es.y += xv[c].y; es.z += xv[c].z; es.w += xv[c].w;
    }
    float4 r;
    r.x = __builtin_amdgcn_rcpf(es.x); r.y = __builtin_amdgcn_rcpf(es.y);
    r.z = __builtin_amdgcn_rcpf(es.z); r.w = __builtin_amdgcn_rcpf(es.w);

    float4 prod = make_float4(1.f, 1.f, 1.f, 1.f);
    #pragma unroll
    for (int c = 0; c < 12; ++c) {
      float4 p;
      p.x = xv[c].x * r.x; p.y = xv[c].y * r.y;
      p.z = xv[c].z * r.z; p.w = xv[c].w * r.w;
      aZ[c] += (p.x*p.x + p.y*p.y) + (p.z*p.z + p.w*p.w);
      aP[c] += (p.x + p.y) + (p.z + p.w);
      if (c > 0) {
        prod.x = fmaf(prod.x, p.x, prod.x);
        prod.y = fmaf(prod.y, p.y, prod.y);
        prod.z = fmaf(prod.z, p.z, prod.z);
        prod.w = fmaf(prod.w, p.w, prod.w);
      }
    }

    // dynamic-index reads from LDS (free) for the two marginal channels
    const float4 v1 = ldsA[id1][tid];
    const float4 vv2 = ldsA[id2c][tid];
    float4 g0, g1, g2;
    g0.x = xv[0].x * r.x; g0.y = xv[0].y * r.y;
    g0.z = xv[0].z * r.z; g0.w = xv[0].w * r.w;
    g1.x = __builtin_amdgcn_exp2f(v1.x * L2E) * r.x;
    g1.y = __builtin_amdgcn_exp2f(v1.y * L2E) * r.y;
    g1.z = __builtin_amdgcn_exp2f(v1.z * L2E) * r.z;
    g1.w = __builtin_amdgcn_exp2f(v1.w * L2E) * r.w;
    g2.x = v2 ? __builtin_amdgcn_exp2f(vv2.x * L2E) * r.x : -1e30f;
    g2.y = v2 ? __builtin_amdgcn_exp2f(vv2.y * L2E) * r.y : -1e30f;
    g2.z = v2 ? __builtin_amdgcn_exp2f(vv2.z * L2E) * r.z : -1e30f;
    g2.w = v2 ? __builtin_amdgcn_exp2f(vv2.w * L2E) * r.w : -1e30f;

    TAIL(x); TAIL(y); TAIL(z); TAIL(w);

    __syncthreads();                      // protect ldsA before next stage
  }

  // ---- block reduction: shuffle tree + tiny LDS ----
  WRED(ces2); WRED(cesE2); WRED(c1f); WRED(c2f);
  WRED(p0S);  WRED(p1S);   WRED(p2S);
  #pragma unroll
  for (int c = 0; c < 12; ++c) { WRED(aZ[c]); WRED(aP[c]); }

  if (lane == 0) {
    float* rw = red[wv];
    #pragma unroll
    for (int c = 0; c < 12; ++c) { rw[c] = aZ[c]; rw[12 + c] = aP[c]; }
    rw[24] = ces2; rw[25] = cesE2; rw[26] = c1f; rw[27] = c2f;
    rw[28] = p0S;  rw[29] = p1S;   rw[30] = p2S; rw[31] = 0.f;
  }
  __syncthreads();
  if (tid < 32) {
    const float sv = red[0][tid] + red[1][tid] + red[2][tid] + red[3][tid];
    atomicAdd(acc + ((b * 32 + tid) << 4), sv);
  }
}

__global__ void finalize(const float* __restrict__ acc,
                         const int* __restrict__ task_id,
                         float* __restrict__ out) {
  if (threadIdx.x != 0) return;
  float lmd = 0.f, lmce = 0.f, led = 0.f, lece = 0.f;
  for (int b = 0; b < 4; ++b) {
    const int t   = task_id[b];
    const int id1 = (t <= 4) ? 2*t + 1 : t + 5;
    const int id2 = (t <= 3) ? 2*t + 2 : -1;
    #define A(v) acc[((b * 32 + (v))) << 4]

    lmce += A(24) * LN2 / NVOX;
    lece += A(25) * LN2 / NVOX;

    const float c1 = A(26), c2 = A(27);
    const float y0 = NVOX - c1 - c2;
    const float d0 = (2.f*A(28) + SMOOTH) / (A(0)   + y0 + SMOOTH);
    const float d1 = (2.f*A(29) + SMOOTH) / (A(id1) + c1 + SMOOTH);
    float d2 = 1.f;
    if (id2 >= 0)
      d2 = (2.f*A(30) + SMOOTH) / (A(id2) + c2 + SMOOTH);
    lmd += (1.f - d0) + (1.f - d1) + (1.f - d2);

    led += SMOOTH / (A(0) + SMOOTH);
    for (int c = 1; c < 12; ++c) {
      const float ptc  = (c == id1) ? A(29) : ((c == id2) ? A(30) : 0.f);
      const float cntc = (c == id1) ? c1    : ((c == id2) ? c2    : 0.f);
      const float inter = A(12 + c) - ptc;
      const float ye    = NVOX - cntc;
      led += (2.f*inter + SMOOTH) / (A(c) + ye + SMOOTH);
    }
    #undef A
  }
  out[0] = lmd  * 0.25f;
  out[1] = lmce * 0.25f;
  out[2] = led  * 0.25f;
  out[3] = lece * 0.25f;
}

extern "C" void kernel_launch(void* const* d_in, const int* in_sizes, int n_in,
                              void* d_out, int out_size, void* d_ws, size_t ws_size,
                              hipStream_t stream) {
  const float* inputs  = (const float*)d_in[0];
  const int*   targets = (const int*)d_in[1];
  const int*   task_id = (const int*)d_in[2];
  float* out = (float*)d_out;
  float* acc = (float*)d_ws;

  zero_acc<<<dim3(8), 256, 0, stream>>>(acc);
  marg_main<<<dim3(4 * BLOCKS_PER_B), THREADS, 0, stream>>>(
      (const float4*)inputs, (const int4*)targets, task_id, acc);
  finalize<<<1, 64, 0, stream>>>(acc, task_id, out);
}